// Round 7
// baseline (269.174 us; speedup 1.0000x reference)
//
#include <hip/hip_runtime.h>

// HashLoss: contrastive (logsumexp over ln@ln^T/0.2) + 0.5*MSE(H@H^T/128, Tn@Tn^T)
//         + 0.01*mean||logits|-1|
// B=4096. P[4096][1024] bf16 = [ln | hash/sqrt128 | tn].
// R7: NO LDS staging, NO K-loop barriers. Each wave owns a 64x64 output tile and
// loads MFMA fragments straight from P (L2/L3-resident) as per-lane 16B row
// chunks. Jobs: 0..2079 = D-role triangle tiles (Hs@Hs^T - T@T^T, K=896);
// 2080..6175 = S-role FULL-square tiles (ln gram, K=128) -> mask read is
// row-coalesced only (no mirror column reads). Finalize fused via done counter:
// per-block RELEASE (writeback only), single ACQUIRE in last block (R4 lesson:
// per-block acquire-invalidate poisons L2).

typedef __bf16 bf16x8 __attribute__((ext_vector_type(8)));
typedef float f32x4 __attribute__((ext_vector_type(4)));

__device__ __forceinline__ unsigned short f2bf(float f) {
  union { float f; unsigned int u; } v; v.f = f;
  unsigned int u = v.u;
  return (unsigned short)((u + 0x7FFFu + ((u >> 16) & 1u)) >> 16);  // RNE
}

// ---- prep: one wave per row. 1024 blocks x 256 threads.
__global__ __launch_bounds__(256) void prep(const float* __restrict__ logits,
                                            const float* __restrict__ hash,
                                            const float* __restrict__ teacher,
                                            unsigned short* __restrict__ P,
                                            float* __restrict__ qpart,
                                            float* __restrict__ rowexp,
                                            float* __restrict__ possum,
                                            float* __restrict__ cntw,
                                            float* __restrict__ dtot,
                                            int* __restrict__ done) {
  const int r = blockIdx.x * 4 + (threadIdx.x >> 6);
  const int lane = threadIdx.x & 63;
  float tv[12];
  float ss = 0.f;
#pragma unroll
  for (int i = 0; i < 12; ++i) {
    tv[i] = teacher[(size_t)r * 768 + i * 64 + lane];
    ss += tv[i] * tv[i];
  }
  const float l0 = logits[(size_t)r * 128 + lane];
  const float l1 = logits[(size_t)r * 128 + 64 + lane];
  const float h0 = hash[(size_t)r * 128 + lane];
  const float h1 = hash[(size_t)r * 128 + 64 + lane];
  float ssl = l0 * l0 + l1 * l1;
  float qv = fabsf(fabsf(l0) - 1.f) + fabsf(fabsf(l1) - 1.f);
#pragma unroll
  for (int off = 1; off < 64; off <<= 1) {
    ss += __shfl_xor(ss, off, 64);
    ssl += __shfl_xor(ssl, off, 64);
    qv += __shfl_xor(qv, off, 64);
  }
  const float rnt = 1.f / fmaxf(sqrtf(ss), 1e-12f);
  const float rnl = 1.f / fmaxf(sqrtf(ssl), 1e-12f);
  unsigned short* Pr = P + (size_t)r * 1024;
  Pr[lane] = f2bf(l0 * rnl);
  Pr[64 + lane] = f2bf(l1 * rnl);
  // (H/sqrt128)@(H/sqrt128)^T == H@H^T/128
  Pr[128 + lane] = f2bf(h0 * 0.08838834764831845f);
  Pr[192 + lane] = f2bf(h1 * 0.08838834764831845f);
#pragma unroll
  for (int i = 0; i < 12; ++i) Pr[256 + i * 64 + lane] = f2bf(tv[i] * rnt);
  if (lane == 0) {
    qpart[r] = qv;
    rowexp[r] = 0.f; possum[r] = 0.f; cntw[r] = 0.f;
    if (r == 0) { *dtot = 0.f; *done = 0; }
  }
}

// Load 4 A-frags + 4 B-frags for one k-step (32 cols at KK). Lane reads
// P[row0 + rt*16 + l15][KK + qd*8 .. +8] = 16B contiguous -> global_load_dwordx4.
#define LOAD8(AA, BB, KK)                                                      \
  _Pragma("unroll") for (int rt = 0; rt < 4; ++rt) {                           \
    AA[rt] = *(const bf16x8*)(Ab + rt * 16384 + (KK));                         \
    BB[rt] = *(const bf16x8*)(Bb + rt * 16384 + (KK));                         \
  }

#define MFMA16(AA, BB)                                                         \
  _Pragma("unroll") for (int rt = 0; rt < 4; ++rt)                             \
      _Pragma("unroll") for (int ct = 0; ct < 4; ++ct) acc[rt][ct] =           \
      __builtin_amdgcn_mfma_f32_16x16x32_bf16(AA[rt], BB[ct], acc[rt][ct], 0,  \
                                              0, 0);

__global__ __launch_bounds__(256, 3) void mega(const unsigned short* __restrict__ P,
                                               const void* __restrict__ mask,
                                               float* __restrict__ rowexp,
                                               float* __restrict__ possum,
                                               float* __restrict__ cntw,
                                               float* __restrict__ dtot,
                                               int* __restrict__ done,
                                               const float* __restrict__ qpart,
                                               float* __restrict__ out) {
  __shared__ float fc[4], fq[4];
  __shared__ int lastf;

  const int t = threadIdx.x;
  const int wave = t >> 6, lane = t & 63;
  const int qd = lane >> 4, l15 = lane & 15;
  const int job = (int)blockIdx.x * 4 + wave;  // 2080 D-jobs, 4096 S-jobs

  f32x4 acc[4][4];
#pragma unroll
  for (int rt = 0; rt < 4; ++rt)
#pragma unroll
    for (int ct = 0; ct < 4; ++ct) acc[rt][ct] = {0.f, 0.f, 0.f, 0.f};

  if (job < 2080) {
    // ---- D-role: triangle decode job -> (bi, bj), bi <= bj over 64 rows ----
    const int l = job;
    int bi = (int)((65.0f - sqrtf(4225.0f - 8.0f * (float)l)) * 0.5f);
    while (bi * (129 - bi) / 2 > l) --bi;
    while ((bi + 1) * (128 - bi) / 2 <= l) ++bi;
    const int bj = bi + (l - bi * (129 - bi) / 2);
    const bool offdiag = (bi != bj);
    const unsigned short* Ab = P + (size_t)(bi * 64 + l15) * 1024 + qd * 8;
    const unsigned short* Bb = P + (size_t)(bj * 64 + l15) * 1024 + qd * 8;

    // T part: cols 256..1023 (24 k-steps, 2 per iter for load/MFMA overlap)
    for (int s = 0; s < 24; s += 2) {
      bf16x8 a0[4], b0[4], a1[4], b1[4];
      LOAD8(a0, b0, 256 + s * 32);
      LOAD8(a1, b1, 288 + s * 32);
      MFMA16(a0, b0);
      MFMA16(a1, b1);
    }
#pragma unroll
    for (int rt = 0; rt < 4; ++rt)
#pragma unroll
      for (int ct = 0; ct < 4; ++ct) acc[rt][ct] = -acc[rt][ct];  // acc = -T
    // Hs part: cols 128..255 (4 k-steps) -> acc = Hs - T
    {
      bf16x8 a0[4], b0[4], a1[4], b1[4];
      LOAD8(a0, b0, 128);
      LOAD8(a1, b1, 160);
      MFMA16(a0, b0);
      MFMA16(a1, b1);
      LOAD8(a0, b0, 192);
      LOAD8(a1, b1, 224);
      MFMA16(a0, b0);
      MFMA16(a1, b1);
    }
    float dsum = 0.f;
#pragma unroll
    for (int rt = 0; rt < 4; ++rt)
#pragma unroll
      for (int ct = 0; ct < 4; ++ct)
#pragma unroll
        for (int i = 0; i < 4; ++i) dsum += acc[rt][ct][i] * acc[rt][ct][i];
#pragma unroll
    for (int off = 1; off < 64; off <<= 1) dsum += __shfl_xor(dsum, off, 64);
    if (lane == 0) atomicAdd(dtot, (offdiag ? 2.0f : 1.0f) * dsum);
  } else {
    // ---- S-role: full-square tile, K=128 ----
    const int sj = job - 2080;
    const int bi = sj >> 6, bj = sj & 63;
    const int ti = bi * 64, tj = bj * 64;
    const unsigned short* Ab = P + (size_t)(ti + l15) * 1024 + qd * 8;
    const unsigned short* Bb = P + (size_t)(tj + l15) * 1024 + qd * 8;
    {
      bf16x8 a0[4], b0[4], a1[4], b1[4];
      LOAD8(a0, b0, 0);
      LOAD8(a1, b1, 32);
      MFMA16(a0, b0);
      MFMA16(a1, b1);
      LOAD8(a0, b0, 64);
      LOAD8(a1, b1, 96);
      MFMA16(a0, b0);
      MFMA16(a1, b1);
    }
    // epilogue: exp/logsumexp rows + sparse positives (row-coalesced mask only)
    const unsigned char* m8 = (const unsigned char*)mask;
    const unsigned int* m32 = (const unsigned int*)mask;
    // byte 4097 = element (1,1) diag (1) if u8 layout; high byte (0) if i32.
    const bool is_byte = m8[4097] != 0;
#pragma unroll
    for (int rt = 0; rt < 4; ++rt) {
#pragma unroll
      for (int r = 0; r < 4; ++r) {
        const int m = ti + rt * 16 + qd * 4 + r;  // C/D: row=(lane>>4)*4+reg
        float se = 0.f;
#pragma unroll
        for (int ct = 0; ct < 4; ++ct) {
          const int n = tj + ct * 16 + l15;       // C/D: col=lane&15
          const float sim = acc[rt][ct][r] * 5.0f;  // /TEMPERATURE
          const float e = __expf(sim);
          if (m != n) se += e;                    // logsumexp excludes diagonal
          const bool pm = is_byte ? (m8[(size_t)m * 4096 + n] != 0)
                                  : (m32[(size_t)m * 4096 + n] != 0);
          if (pm) {                               // sparse (~9/tile): direct atomics
            atomicAdd(&possum[m], sim);
            atomicAdd(&cntw[m], 1.0f);
          }
        }
#pragma unroll
        for (int off = 1; off < 16; off <<= 1) se += __shfl_xor(se, off, 64);
        if (l15 == 0) atomicAdd(&rowexp[m], se);
      }
    }
  }

  // ---- done counter: per-block RELEASE (wb only); last block ACQUIREs once --
  __syncthreads();
  if (t == 0) {
    const int old = __hip_atomic_fetch_add(done, 1, __ATOMIC_RELEASE,
                                           __HIP_MEMORY_SCOPE_AGENT);
    if (old == 1543) {
      (void)__hip_atomic_load(done, __ATOMIC_ACQUIRE, __HIP_MEMORY_SCOPE_AGENT);
      lastf = 1;
    } else {
      lastf = 0;
    }
  }
  __syncthreads();
  if (lastf) {
    float c = 0.f, q = 0.f;
    for (int m = t; m < 4096; m += 256) {
      c += logf(rowexp[m]) - possum[m] / fmaxf(cntw[m], 1.0f);
      q += qpart[m];
    }
#pragma unroll
    for (int off = 1; off < 64; off <<= 1) {
      c += __shfl_xor(c, off, 64);
      q += __shfl_xor(q, off, 64);
    }
    if (lane == 0) { fc[wave] = c; fq[wave] = q; }
    __syncthreads();
    if (t == 0) {
      const float C = fc[0] + fc[1] + fc[2] + fc[3];
      const float Q = fq[0] + fq[1] + fq[2] + fq[3];
      // num_pos = B (diagonal positives guaranteed)
      out[0] = C * (1.0f / 4096.0f) + 0.5f * (dtot[0] * (1.0f / 16777216.0f)) +
               0.01f * (Q * (1.0f / 524288.0f));
    }
  }
}

extern "C" void kernel_launch(void* const* d_in, const int* in_sizes, int n_in,
                              void* d_out, int out_size, void* d_ws, size_t ws_size,
                              hipStream_t stream) {
  const float* logits = (const float*)d_in[0];
  const float* hash = (const float*)d_in[1];
  const float* teacher = (const float*)d_in[2];
  const void* mask = d_in[3];
  float* out = (float*)d_out;

  char* ws = (char*)d_ws;
  float* rowexp = (float*)(ws + 0);
  float* possum = (float*)(ws + 16384);
  float* cntw = (float*)(ws + 32768);
  float* qpart = (float*)(ws + 49152);
  float* dtot = (float*)(ws + 65536);
  int* done = (int*)(ws + 65544);
  unsigned short* P = (unsigned short*)(ws + 98304);  // 4096x1024 bf16 = 8 MB

  prep<<<1024, 256, 0, stream>>>(logits, hash, teacher, P, qpart, rowexp,
                                 possum, cntw, dtot, done);
  // 2080 D-jobs + 4096 S-jobs = 6176 waves = 1544 blocks x 4 waves
  mega<<<1544, 256, 0, stream>>>(P, mask, rowexp, possum, cntw, dtot, done,
                                 qpart, out);
}

// Round 8
// 187.681 us; speedup vs baseline: 1.4342x; 1.4342x over previous
//
#include <hip/hip_runtime.h>

// HashLoss: contrastive (logsumexp over ln@ln^T/0.2) + 0.5*MSE(H@H^T/128, Tn@Tn^T)
//         + 0.01*mean||logits|-1|
// B=4096. R8 = R5 structure (best mega: LDS-staged, cross-wave shared, 128x128
// tiles, role-split) with:
//  - D-Gram in fp8 e4m3: Q[4096][896] = [H(+-1 exact) | tn*sqrt(128)].
//    acc = H@H^T - 128*tn@tn^T; final scale /16384 extra. 7 chunks (was 14),
//    staged bytes halved, Q(3.5MB)+P(1MB) fit per-XCD L2.
//  - S-Gram stays bf16: P[4096][128] = ln.
//  - finalize fused via done-counter: per-block RELEASE add, single ACQUIRE in
//    last block (R7-proven; R4's per-block acquire-invalidate poisons L2).

typedef __bf16 bf16x8 __attribute__((ext_vector_type(8)));
typedef float f32x4 __attribute__((ext_vector_type(4)));

__device__ __forceinline__ unsigned short f2bf(float f) {
  union { float f; unsigned int u; } v; v.f = f;
  unsigned int u = v.u;
  return (unsigned short)((u + 0x7FFFu + ((u >> 16) & 1u)) >> 16);  // RNE
}

// ---- prep: one wave per row, no LDS. 1024 blocks x 256 threads.
__global__ __launch_bounds__(256) void prep(const float* __restrict__ logits,
                                            const float* __restrict__ hash,
                                            const float* __restrict__ teacher,
                                            unsigned short* __restrict__ P,
                                            unsigned char* __restrict__ Q,
                                            float* __restrict__ qpart,
                                            float* __restrict__ rowexp,
                                            float* __restrict__ possum,
                                            float* __restrict__ cntw,
                                            float* __restrict__ dtot,
                                            int* __restrict__ done) {
  const int r = blockIdx.x * 4 + (threadIdx.x >> 6);
  const int lane = threadIdx.x & 63;
  // teacher: 6 groups of 128 cols; lane owns cols 2*lane, 2*lane+1
  float2 tv[6];
  float ss = 0.f;
#pragma unroll
  for (int i = 0; i < 6; ++i) {
    tv[i] = *(const float2*)&teacher[(size_t)r * 768 + i * 128 + 2 * lane];
    ss += tv[i].x * tv[i].x + tv[i].y * tv[i].y;
  }
  const float2 lv = *(const float2*)&logits[(size_t)r * 128 + 2 * lane];
  const float2 hv = *(const float2*)&hash[(size_t)r * 128 + 2 * lane];
  float ssl = lv.x * lv.x + lv.y * lv.y;
  float qv = fabsf(fabsf(lv.x) - 1.f) + fabsf(fabsf(lv.y) - 1.f);
#pragma unroll
  for (int off = 1; off < 64; off <<= 1) {
    ss += __shfl_xor(ss, off, 64);
    ssl += __shfl_xor(ssl, off, 64);
    qv += __shfl_xor(qv, off, 64);
  }
  // teacher scaled by sqrt(128)/||t||: Gram gives 128 * tn@tn^T
  const float rnt = 11.313708498984761f / fmaxf(sqrtf(ss), 1e-12f);
  const float rnl = 1.f / fmaxf(sqrtf(ssl), 1e-12f);
  // P: normalized logits, bf16
  unsigned int pb = (unsigned int)f2bf(lv.x * rnl) |
                    ((unsigned int)f2bf(lv.y * rnl) << 16);
  *(unsigned int*)&P[(size_t)r * 128 + 2 * lane] = pb;
  // Q cols 0..127: hash as exact +-1.0 in e4m3 (0x38 / 0xB8)
  unsigned short hb = (unsigned short)((hv.x >= 0.f ? 0x38 : 0xB8) |
                                       ((hv.y >= 0.f ? 0x38 : 0xB8) << 8));
  *(unsigned short*)&Q[(size_t)r * 896 + 2 * lane] = hb;
  // Q cols 128..895: teacher*sqrt128*rn, fp8 e4m3 (RNE pack)
#pragma unroll
  for (int i = 0; i < 6; ++i) {
    int p = __builtin_amdgcn_cvt_pk_fp8_f32(tv[i].x * rnt, tv[i].y * rnt, 0, false);
    *(unsigned short*)&Q[(size_t)r * 896 + 128 + i * 128 + 2 * lane] =
        (unsigned short)(p & 0xFFFF);
  }
  if (lane == 0) {
    qpart[r] = qv;
    rowexp[r] = 0.f; possum[r] = 0.f; cntw[r] = 0.f;
    if (r == 0) { *dtot = 0.f; *done = 0; }
  }
}

// Stage 128 rows x 128 BYTES from gA (and gB if offdiag) into LDS bytes
// [0..16K) / [16K..32K). LDS 16B-slot p of row holds global chunk p^(row&7).
#define STAGE_GEN(GA, GB, PITCH)                                               \
  {                                                                            \
    _Pragma("unroll") for (int it = 0; it < 4; ++it) {                         \
      const int task = it * 256 + t;                                           \
      const int row = task >> 3;                                               \
      const int c16 = (task & 7) ^ (row & 7);                                  \
      const unsigned char* gpA = (GA) + (size_t)row * (PITCH) + c16 * 16;      \
      __builtin_amdgcn_global_load_lds(                                        \
          (const __attribute__((address_space(1))) void*)gpA,                  \
          (__attribute__((address_space(3))) void*)&SB[it * 4096 + wave * 1024],\
          16, 0, 0);                                                           \
      if (offdiag) {                                                           \
        const unsigned char* gpB = (GB) + (size_t)row * (PITCH) + c16 * 16;    \
        __builtin_amdgcn_global_load_lds(                                      \
            (const __attribute__((address_space(1))) void*)gpB,                \
            (__attribute__((address_space(3)))                                 \
                 void*)&SB[16384 + it * 4096 + wave * 1024],                   \
            16, 0, 0);                                                         \
      }                                                                        \
    }                                                                          \
  }

// bf16 chunk (64 cols = 2 ksteps), 16 MFMA each. Wave (wy,wx) owns 64x64 quad.
#define MFMA_B()                                                               \
  {                                                                            \
    _Pragma("unroll") for (int ks = 0; ks < 2; ++ks) {                         \
      const int ph = ((ks * 4 + qd) ^ (l15 & 7)) * 16;                         \
      bf16x8 af[4], bfr[4];                                                    \
      _Pragma("unroll") for (int rt = 0; rt < 4; ++rt)                         \
          af[rt] = *(const bf16x8*)&SB[(wy * 64 + rt * 16 + l15) * 128 + ph];  \
      _Pragma("unroll") for (int ct = 0; ct < 4; ++ct)                         \
          bfr[ct] = *(const bf16x8*)&SB[boffB +                                \
                                        (wx * 64 + ct * 16 + l15) * 128 + ph]; \
      _Pragma("unroll") for (int rt = 0; rt < 4; ++rt)                         \
          _Pragma("unroll") for (int ct = 0; ct < 4; ++ct) acc[rt][ct] =       \
          __builtin_amdgcn_mfma_f32_16x16x32_bf16(af[rt], bfr[ct],             \
                                                  acc[rt][ct], 0, 0, 0);       \
    }                                                                          \
  }

// fp8 chunk (128 cols = 4 ksteps), 16 MFMA each; 8B frags (ds_read_b64).
#define MFMA_Q()                                                               \
  {                                                                            \
    _Pragma("unroll") for (int ks = 0; ks < 4; ++ks) {                         \
      const int g0 = ks * 4 + qd;                                              \
      const int ph = ((g0 >> 1) ^ (l15 & 7)) * 16 + (g0 & 1) * 8;              \
      long af[4], bfr[4];                                                      \
      _Pragma("unroll") for (int rt = 0; rt < 4; ++rt)                         \
          af[rt] = *(const long*)&SB[(wy * 64 + rt * 16 + l15) * 128 + ph];    \
      _Pragma("unroll") for (int ct = 0; ct < 4; ++ct)                         \
          bfr[ct] = *(const long*)&SB[boffB +                                  \
                                      (wx * 64 + ct * 16 + l15) * 128 + ph];   \
      _Pragma("unroll") for (int rt = 0; rt < 4; ++rt)                         \
          _Pragma("unroll") for (int ct = 0; ct < 4; ++ct) acc[rt][ct] =       \
          __builtin_amdgcn_mfma_f32_16x16x32_fp8_fp8(af[rt], bfr[ct],          \
                                                     acc[rt][ct], 0, 0, 0);    \
    }                                                                          \
  }

__global__ __launch_bounds__(256, 3) void mega(const unsigned short* __restrict__ P,
                                               const unsigned char* __restrict__ Q,
                                               const void* __restrict__ mask,
                                               float* __restrict__ rowexp,
                                               float* __restrict__ possum,
                                               float* __restrict__ cntw,
                                               float* __restrict__ dtot,
                                               int* __restrict__ done,
                                               const float* __restrict__ qpart,
                                               float* __restrict__ out) {
  __shared__ __align__(16) unsigned char SB[32768];  // A @0, B @16384
  __shared__ float redrow[128][2], redcol[128][2], red4[4];
  __shared__ float fc[4], fq[4];
  __shared__ int lastf;

  const int t = threadIdx.x;
  const int wave = t >> 6, lane = t & 63;
  const int qd = lane >> 4, l15 = lane & 15;
  const int wy = wave >> 1, wx = wave & 1;

  const int b = (int)blockIdx.x;
  const bool isD = (b & 1) == 0;          // interleave roles for CU balance
  const int bb = b >> 1;
  // XCD swizzle (528 = 8*66), then triangle decode over 32 block-rows.
  const int l = (bb & 7) * 66 + (bb >> 3);
  int bi = (int)((65.0f - sqrtf(4225.0f - 8.0f * (float)l)) * 0.5f);
  while (bi * (65 - bi) / 2 > l) --bi;
  while ((bi + 1) * (64 - bi) / 2 <= l) ++bi;
  const int bj = bi + (l - bi * (65 - bi) / 2);
  const int ti = bi * 128, tj = bj * 128;
  const bool offdiag = (bi != bj);
  const int boffB = offdiag ? 16384 : 0;

  f32x4 acc[4][4];
#pragma unroll
  for (int rt = 0; rt < 4; ++rt)
#pragma unroll
    for (int ct = 0; ct < 4; ++ct) acc[rt][ct] = {0.f, 0.f, 0.f, 0.f};

  if (isD) {
    // acc = H@H^T - 128*tn@tn^T: chunks 0..5 = T part (Q bytes 128..895),
    // negate, chunk 6 = H part (Q bytes 0..127).
    const unsigned char* Qa = Q + (size_t)ti * 896;
    const unsigned char* Qb = Q + (size_t)tj * 896;
    for (int kc = 0; kc < 7; ++kc) {
      const int off = (kc < 6) ? (128 + kc * 128) : 0;
      __syncthreads();
      STAGE_GEN(Qa + off, Qb + off, 896);
      __syncthreads();
      if (kc == 6) {
#pragma unroll
        for (int rt = 0; rt < 4; ++rt)
#pragma unroll
          for (int ct = 0; ct < 4; ++ct) acc[rt][ct] = -acc[rt][ct];
      }
      MFMA_Q();
    }
    float dsum = 0.f;
#pragma unroll
    for (int rt = 0; rt < 4; ++rt)
#pragma unroll
      for (int ct = 0; ct < 4; ++ct)
#pragma unroll
        for (int i = 0; i < 4; ++i) dsum += acc[rt][ct][i] * acc[rt][ct][i];
#pragma unroll
    for (int off = 1; off < 64; off <<= 1) dsum += __shfl_xor(dsum, off, 64);
    if (lane == 0) red4[wave] = dsum;
    __syncthreads();
    if (t == 0)
      atomicAdd(dtot, (offdiag ? 2.0f : 1.0f) *
                          (red4[0] + red4[1] + red4[2] + red4[3]));
  } else {
    // S-role: ln gram (bf16), K=128 = 2 chunks of 64 cols.
    const unsigned char* Pa = (const unsigned char*)(P + (size_t)ti * 128);
    const unsigned char* Pb = (const unsigned char*)(P + (size_t)tj * 128);
    for (int kc = 0; kc < 2; ++kc) {
      __syncthreads();
      STAGE_GEN(Pa + kc * 128, Pb + kc * 128, 256);
      __syncthreads();
      MFMA_B();
    }

    // ---- mask tiles -> LDS (coalesced), reusing SB ----
    __syncthreads();
    unsigned char* MD = SB;          // [mrow][ncol], 16KB
    unsigned char* MM = SB + 16384;  // [ncol][mrow], 16KB
    const bool is_byte = ((const unsigned char*)mask)[4097] != 0;
    if (is_byte) {
      const unsigned char* m8 = (const unsigned char*)mask;
#pragma unroll
      for (int it = 0; it < 4; ++it) {
        const int task = it * 256 + t;
        const int row = task >> 3, seg = task & 7;
        *(uint4*)&MD[row * 128 + seg * 16] =
            *(const uint4*)&m8[(size_t)(ti + row) * 4096 + tj + seg * 16];
        if (offdiag)
          *(uint4*)&MM[row * 128 + seg * 16] =
              *(const uint4*)&m8[(size_t)(tj + row) * 4096 + ti + seg * 16];
      }
    } else {
      const unsigned int* m32 = (const unsigned int*)mask;
#pragma unroll
      for (int it = 0; it < 16; ++it) {
        const int task = it * 256 + t;
        const int row = task >> 5, seg = task & 31;
        uint4 v = *(const uint4*)&m32[(size_t)(ti + row) * 4096 + tj + seg * 4];
        uchar4 pk;
        pk.x = v.x ? 1 : 0; pk.y = v.y ? 1 : 0;
        pk.z = v.z ? 1 : 0; pk.w = v.w ? 1 : 0;
        *(uchar4*)&MD[row * 128 + seg * 4] = pk;
        if (offdiag) {
          uint4 w = *(const uint4*)&m32[(size_t)(tj + row) * 4096 + ti + seg * 4];
          uchar4 pm;
          pm.x = w.x ? 1 : 0; pm.y = w.y ? 1 : 0;
          pm.z = w.z ? 1 : 0; pm.w = w.w ? 1 : 0;
          *(uchar4*)&MM[row * 128 + seg * 4] = pm;
        }
      }
    }
    __syncthreads();

    float colp[4] = {0.f, 0.f, 0.f, 0.f};
#pragma unroll
    for (int rt = 0; rt < 4; ++rt) {
#pragma unroll
      for (int r = 0; r < 4; ++r) {
        const int mrow = wy * 64 + rt * 16 + qd * 4 + r;  // C/D: row=qd*4+reg
        const int m = ti + mrow;
        float se = 0.f;
#pragma unroll
        for (int ct = 0; ct < 4; ++ct) {
          const int ncol = wx * 64 + ct * 16 + l15;        // C/D: col=lane&15
          const int n = tj + ncol;
          const float sim = acc[rt][ct][r] * 5.0f;         // /TEMPERATURE
          const float e = __expf(sim);
          if (offdiag || mrow != ncol) se += e;            // diag excluded
          if (offdiag) colp[ct] += e;
          if (MD[mrow * 128 + ncol]) {                     // sparse positives
            atomicAdd(&possum[m], sim);
            atomicAdd(&cntw[m], 1.0f);
          }
          if (offdiag && MM[ncol * 128 + mrow]) {          // mirror (n, m)
            atomicAdd(&possum[n], sim);
            atomicAdd(&cntw[n], 1.0f);
          }
        }
#pragma unroll
        for (int off = 1; off < 16; off <<= 1) se += __shfl_xor(se, off, 64);
        if (l15 == 0) redrow[mrow][wx] = se;
      }
    }
    if (offdiag) {
#pragma unroll
      for (int ct = 0; ct < 4; ++ct) {
        float ce = colp[ct];
        ce += __shfl_xor(ce, 16, 64);
        ce += __shfl_xor(ce, 32, 64);
        if (qd == 0) redcol[wx * 64 + ct * 16 + l15][wy] = ce;
      }
    }
    __syncthreads();
    if (t < 128) {
      atomicAdd(&rowexp[ti + t], redrow[t][0] + redrow[t][1]);
      if (offdiag) atomicAdd(&rowexp[tj + t], redcol[t][0] + redcol[t][1]);
    }
  }

  // ---- done counter: per-block RELEASE add; last block ACQUIREs once ----
  __syncthreads();
  if (t == 0) {
    const int old = __hip_atomic_fetch_add(done, 1, __ATOMIC_RELEASE,
                                           __HIP_MEMORY_SCOPE_AGENT);
    if (old == 1055) {
      (void)__hip_atomic_load(done, __ATOMIC_ACQUIRE, __HIP_MEMORY_SCOPE_AGENT);
      lastf = 1;
    } else {
      lastf = 0;
    }
  }
  __syncthreads();
  if (lastf) {
    float c = 0.f, q = 0.f;
    for (int m = t; m < 4096; m += 256) {
      c += logf(rowexp[m]) - possum[m] / fmaxf(cntw[m], 1.0f);
      q += qpart[m];
    }
#pragma unroll
    for (int off = 1; off < 64; off <<= 1) {
      c += __shfl_xor(c, off, 64);
      q += __shfl_xor(q, off, 64);
    }
    if (lane == 0) { fc[wave] = c; fq[wave] = q; }
    __syncthreads();
    if (t == 0) {
      const float C = fc[0] + fc[1] + fc[2] + fc[3];
      const float Q_ = fq[0] + fq[1] + fq[2] + fq[3];
      // D entries are 128x the true diff -> extra /16384 on the squared sum:
      // 0.5 * dtot / (4096^2 * 16384) = dtot * 0.5 * 3.6379788e-12
      out[0] = C * (1.0f / 4096.0f) + 0.5f * (dtot[0] * 3.6379788e-12f) +
               0.01f * (Q_ * (1.0f / 524288.0f));
    }
  }
}

extern "C" void kernel_launch(void* const* d_in, const int* in_sizes, int n_in,
                              void* d_out, int out_size, void* d_ws, size_t ws_size,
                              hipStream_t stream) {
  const float* logits = (const float*)d_in[0];
  const float* hash = (const float*)d_in[1];
  const float* teacher = (const float*)d_in[2];
  const void* mask = d_in[3];
  float* out = (float*)d_out;

  char* ws = (char*)d_ws;
  float* rowexp = (float*)(ws + 0);
  float* possum = (float*)(ws + 16384);
  float* cntw = (float*)(ws + 32768);
  float* qpart = (float*)(ws + 49152);
  float* dtot = (float*)(ws + 65536);
  int* done = (int*)(ws + 65544);
  unsigned short* P = (unsigned short*)(ws + 98304);      // 4096x128 bf16 = 1 MB
  unsigned char* Q = (unsigned char*)(ws + 98304 + 1048576);  // 4096x896 fp8 = 3.5 MB

  prep<<<1024, 256, 0, stream>>>(logits, hash, teacher, P, Q, qpart, rowexp,
                                 possum, cntw, dtot, done);
  mega<<<1056, 256, 0, stream>>>(P, Q, mask, rowexp, possum, cntw, dtot, done,
                                 qpart, out);
}

// Round 9
// 173.448 us; speedup vs baseline: 1.5519x; 1.0821x over previous
//
#include <hip/hip_runtime.h>

// HashLoss: contrastive (logsumexp over ln@ln^T/0.2) + 0.5*MSE(H@H^T/128, Tn@Tn^T)
//         + 0.01*mean||logits|-1|
// B=4096. R9 = R5 structure (best mega) + fp8 D-Gram (R8-verified numerics),
// finalize back to its OWN dispatch: NO release/acquire/fence ops inside mega
// (R4: per-block acquire-invalidate catastrophic; R8: per-block release-writeback
// +13us). Relaxed atomicAdd only. Mask (u8 path) staged via global_load_lds.
//  - D-role blocks: 128x128 triangle tiles of Q@Q^T where Q = [H(+-1) | tn*sqrt128]
//    fp8 e4m3 -> acc = H@H^T - 128*tn@tn^T (negate-between-parts trick).
//  - S-role blocks: 128x128 triangle tiles of ln@ln^T (bf16) + mask epilogue.

typedef __bf16 bf16x8 __attribute__((ext_vector_type(8)));
typedef float f32x4 __attribute__((ext_vector_type(4)));

__device__ __forceinline__ unsigned short f2bf(float f) {
  union { float f; unsigned int u; } v; v.f = f;
  unsigned int u = v.u;
  return (unsigned short)((u + 0x7FFFu + ((u >> 16) & 1u)) >> 16);  // RNE
}

// ---- prep: one wave per row, no LDS. 1024 blocks x 256 threads.
__global__ __launch_bounds__(256) void prep(const float* __restrict__ logits,
                                            const float* __restrict__ hash,
                                            const float* __restrict__ teacher,
                                            unsigned short* __restrict__ P,
                                            unsigned char* __restrict__ Q,
                                            float* __restrict__ qpart,
                                            float* __restrict__ rowexp,
                                            float* __restrict__ possum,
                                            float* __restrict__ cntw,
                                            float* __restrict__ dtot) {
  const int r = blockIdx.x * 4 + (threadIdx.x >> 6);
  const int lane = threadIdx.x & 63;
  float2 tv[6];
  float ss = 0.f;
#pragma unroll
  for (int i = 0; i < 6; ++i) {
    tv[i] = *(const float2*)&teacher[(size_t)r * 768 + i * 128 + 2 * lane];
    ss += tv[i].x * tv[i].x + tv[i].y * tv[i].y;
  }
  const float2 lv = *(const float2*)&logits[(size_t)r * 128 + 2 * lane];
  const float2 hv = *(const float2*)&hash[(size_t)r * 128 + 2 * lane];
  float ssl = lv.x * lv.x + lv.y * lv.y;
  float qv = fabsf(fabsf(lv.x) - 1.f) + fabsf(fabsf(lv.y) - 1.f);
#pragma unroll
  for (int off = 1; off < 64; off <<= 1) {
    ss += __shfl_xor(ss, off, 64);
    ssl += __shfl_xor(ssl, off, 64);
    qv += __shfl_xor(qv, off, 64);
  }
  // teacher scaled by sqrt(128)/||t||: Gram gives 128 * tn@tn^T
  const float rnt = 11.313708498984761f / fmaxf(sqrtf(ss), 1e-12f);
  const float rnl = 1.f / fmaxf(sqrtf(ssl), 1e-12f);
  unsigned int pb = (unsigned int)f2bf(lv.x * rnl) |
                    ((unsigned int)f2bf(lv.y * rnl) << 16);
  *(unsigned int*)&P[(size_t)r * 128 + 2 * lane] = pb;
  // Q cols 0..127: hash as exact +-1.0 in e4m3 (0x38 / 0xB8)
  unsigned short hb = (unsigned short)((hv.x >= 0.f ? 0x38 : 0xB8) |
                                       ((hv.y >= 0.f ? 0x38 : 0xB8) << 8));
  *(unsigned short*)&Q[(size_t)r * 896 + 2 * lane] = hb;
#pragma unroll
  for (int i = 0; i < 6; ++i) {
    int p = __builtin_amdgcn_cvt_pk_fp8_f32(tv[i].x * rnt, tv[i].y * rnt, 0, false);
    *(unsigned short*)&Q[(size_t)r * 896 + 128 + i * 128 + 2 * lane] =
        (unsigned short)(p & 0xFFFF);
  }
  if (lane == 0) {
    qpart[r] = qv;
    rowexp[r] = 0.f; possum[r] = 0.f; cntw[r] = 0.f;
    if (r == 0) *dtot = 0.f;
  }
}

// Stage 128 rows x 128 BYTES from gA (and gB if offdiag) into LDS bytes
// [0..16K) / [16K..32K). LDS 16B-slot p of row holds global chunk p^(row&7).
#define STAGE_GEN(GA, GB, PITCH)                                               \
  {                                                                            \
    _Pragma("unroll") for (int it = 0; it < 4; ++it) {                         \
      const int task = it * 256 + t;                                           \
      const int row = task >> 3;                                               \
      const int c16 = (task & 7) ^ (row & 7);                                  \
      const unsigned char* gpA = (GA) + (size_t)row * (PITCH) + c16 * 16;      \
      __builtin_amdgcn_global_load_lds(                                        \
          (const __attribute__((address_space(1))) void*)gpA,                  \
          (__attribute__((address_space(3))) void*)&SB[it * 4096 + wave * 1024],\
          16, 0, 0);                                                           \
      if (offdiag) {                                                           \
        const unsigned char* gpB = (GB) + (size_t)row * (PITCH) + c16 * 16;    \
        __builtin_amdgcn_global_load_lds(                                      \
            (const __attribute__((address_space(1))) void*)gpB,                \
            (__attribute__((address_space(3)))                                 \
                 void*)&SB[16384 + it * 4096 + wave * 1024],                   \
            16, 0, 0);                                                         \
      }                                                                        \
    }                                                                          \
  }

// bf16 chunk (64 cols = 2 ksteps), 16 MFMA each. Wave (wy,wx) owns 64x64 quad.
#define MFMA_B()                                                               \
  {                                                                            \
    _Pragma("unroll") for (int ks = 0; ks < 2; ++ks) {                         \
      const int ph = ((ks * 4 + qd) ^ (l15 & 7)) * 16;                         \
      bf16x8 af[4], bfr[4];                                                    \
      _Pragma("unroll") for (int rt = 0; rt < 4; ++rt)                         \
          af[rt] = *(const bf16x8*)&SB[(wy * 64 + rt * 16 + l15) * 128 + ph];  \
      _Pragma("unroll") for (int ct = 0; ct < 4; ++ct)                         \
          bfr[ct] = *(const bf16x8*)&SB[boffB +                                \
                                        (wx * 64 + ct * 16 + l15) * 128 + ph]; \
      _Pragma("unroll") for (int rt = 0; rt < 4; ++rt)                         \
          _Pragma("unroll") for (int ct = 0; ct < 4; ++ct) acc[rt][ct] =       \
          __builtin_amdgcn_mfma_f32_16x16x32_bf16(af[rt], bfr[ct],             \
                                                  acc[rt][ct], 0, 0, 0);       \
    }                                                                          \
  }

// fp8 chunk (128 cols = 4 ksteps), 16 MFMA each; 8B frags.
#define MFMA_Q()                                                               \
  {                                                                            \
    _Pragma("unroll") for (int ks = 0; ks < 4; ++ks) {                         \
      const int g0 = ks * 4 + qd;                                              \
      const int ph = ((g0 >> 1) ^ (l15 & 7)) * 16 + (g0 & 1) * 8;              \
      long af[4], bfr[4];                                                      \
      _Pragma("unroll") for (int rt = 0; rt < 4; ++rt)                         \
          af[rt] = *(const long*)&SB[(wy * 64 + rt * 16 + l15) * 128 + ph];    \
      _Pragma("unroll") for (int ct = 0; ct < 4; ++ct)                         \
          bfr[ct] = *(const long*)&SB[boffB +                                  \
                                      (wx * 64 + ct * 16 + l15) * 128 + ph];   \
      _Pragma("unroll") for (int rt = 0; rt < 4; ++rt)                         \
          _Pragma("unroll") for (int ct = 0; ct < 4; ++ct) acc[rt][ct] =       \
          __builtin_amdgcn_mfma_f32_16x16x32_fp8_fp8(af[rt], bfr[ct],          \
                                                     acc[rt][ct], 0, 0, 0);    \
    }                                                                          \
  }

__global__ __launch_bounds__(256, 3) void mega(const unsigned short* __restrict__ P,
                                               const unsigned char* __restrict__ Q,
                                               const void* __restrict__ mask,
                                               float* __restrict__ rowexp,
                                               float* __restrict__ possum,
                                               float* __restrict__ cntw,
                                               float* __restrict__ dtot) {
  __shared__ __align__(16) unsigned char SB[32768];  // A @0, B @16384
  __shared__ float redrow[128][2], redcol[128][2], red4[4];

  const int t = threadIdx.x;
  const int wave = t >> 6, lane = t & 63;
  const int qd = lane >> 4, l15 = lane & 15;
  const int wy = wave >> 1, wx = wave & 1;

  const int b = (int)blockIdx.x;
  const bool isD = (b & 1) == 0;          // interleave roles for CU balance
  const int bb = b >> 1;
  // XCD swizzle (528 = 8*66), then triangle decode over 32 block-rows.
  const int l = (bb & 7) * 66 + (bb >> 3);
  int bi = (int)((65.0f - sqrtf(4225.0f - 8.0f * (float)l)) * 0.5f);
  while (bi * (65 - bi) / 2 > l) --bi;
  while ((bi + 1) * (64 - bi) / 2 <= l) ++bi;
  const int bj = bi + (l - bi * (65 - bi) / 2);
  const int ti = bi * 128, tj = bj * 128;
  const bool offdiag = (bi != bj);
  const int boffB = offdiag ? 16384 : 0;

  f32x4 acc[4][4];
#pragma unroll
  for (int rt = 0; rt < 4; ++rt)
#pragma unroll
    for (int ct = 0; ct < 4; ++ct) acc[rt][ct] = {0.f, 0.f, 0.f, 0.f};

  if (isD) {
    // acc = H@H^T - 128*tn@tn^T: chunks 0..5 = T part (Q bytes 128..895),
    // negate, chunk 6 = H part (Q bytes 0..127).
    const unsigned char* Qa = Q + (size_t)ti * 896;
    const unsigned char* Qb = Q + (size_t)tj * 896;
    for (int kc = 0; kc < 7; ++kc) {
      const int off = (kc < 6) ? (128 + kc * 128) : 0;
      __syncthreads();
      STAGE_GEN(Qa + off, Qb + off, 896);
      __syncthreads();
      if (kc == 6) {
#pragma unroll
        for (int rt = 0; rt < 4; ++rt)
#pragma unroll
          for (int ct = 0; ct < 4; ++ct) acc[rt][ct] = -acc[rt][ct];
      }
      MFMA_Q();
    }
    float dsum = 0.f;
#pragma unroll
    for (int rt = 0; rt < 4; ++rt)
#pragma unroll
      for (int ct = 0; ct < 4; ++ct)
#pragma unroll
        for (int i = 0; i < 4; ++i) dsum += acc[rt][ct][i] * acc[rt][ct][i];
#pragma unroll
    for (int off = 1; off < 64; off <<= 1) dsum += __shfl_xor(dsum, off, 64);
    if (lane == 0) red4[wave] = dsum;
    __syncthreads();
    if (t == 0)
      atomicAdd(dtot, (offdiag ? 2.0f : 1.0f) *
                          (red4[0] + red4[1] + red4[2] + red4[3]));
  } else {
    // S-role: ln gram (bf16), K=128 = 2 chunks of 64 cols.
    const unsigned char* Pa = (const unsigned char*)(P + (size_t)ti * 128);
    const unsigned char* Pb = (const unsigned char*)(P + (size_t)tj * 128);
    for (int kc = 0; kc < 2; ++kc) {
      __syncthreads();
      STAGE_GEN(Pa + kc * 128, Pb + kc * 128, 256);
      __syncthreads();
      MFMA_B();
    }

    // ---- mask tiles -> LDS, reusing SB ----
    __syncthreads();
    unsigned char* MD = SB;          // [mrow][ncol], 16KB
    unsigned char* MM = SB + 16384;  // [ncol][mrow], 16KB
    const bool is_byte = ((const unsigned char*)mask)[4097] != 0;
    if (is_byte) {
      // DMA staging: identity layout (no XOR) -> lds[task*16] = row*128+seg*16
      const unsigned char* m8d = (const unsigned char*)mask + (size_t)ti * 4096 + tj;
      const unsigned char* m8m = (const unsigned char*)mask + (size_t)tj * 4096 + ti;
#pragma unroll
      for (int it = 0; it < 4; ++it) {
        const int task = it * 256 + t;
        const int row = task >> 3, seg = task & 7;
        __builtin_amdgcn_global_load_lds(
            (const __attribute__((address_space(1))) void*)
                (m8d + (size_t)row * 4096 + seg * 16),
            (__attribute__((address_space(3))) void*)&MD[it * 4096 + wave * 1024],
            16, 0, 0);
        if (offdiag)
          __builtin_amdgcn_global_load_lds(
              (const __attribute__((address_space(1))) void*)
                  (m8m + (size_t)row * 4096 + seg * 16),
              (__attribute__((address_space(3))) void*)&MM[it * 4096 + wave * 1024],
              16, 0, 0);
      }
    } else {
      const unsigned int* m32 = (const unsigned int*)mask;
#pragma unroll
      for (int it = 0; it < 16; ++it) {
        const int task = it * 256 + t;
        const int row = task >> 5, seg = task & 31;
        uint4 v = *(const uint4*)&m32[(size_t)(ti + row) * 4096 + tj + seg * 4];
        uchar4 pk;
        pk.x = v.x ? 1 : 0; pk.y = v.y ? 1 : 0;
        pk.z = v.z ? 1 : 0; pk.w = v.w ? 1 : 0;
        *(uchar4*)&MD[row * 128 + seg * 4] = pk;
        if (offdiag) {
          uint4 w = *(const uint4*)&m32[(size_t)(tj + row) * 4096 + ti + seg * 4];
          uchar4 pm;
          pm.x = w.x ? 1 : 0; pm.y = w.y ? 1 : 0;
          pm.z = w.z ? 1 : 0; pm.w = w.w ? 1 : 0;
          *(uchar4*)&MM[row * 128 + seg * 4] = pm;
        }
      }
    }
    __syncthreads();

    float colp[4] = {0.f, 0.f, 0.f, 0.f};
#pragma unroll
    for (int rt = 0; rt < 4; ++rt) {
#pragma unroll
      for (int r = 0; r < 4; ++r) {
        const int mrow = wy * 64 + rt * 16 + qd * 4 + r;  // C/D: row=qd*4+reg
        const int m = ti + mrow;
        float se = 0.f;
#pragma unroll
        for (int ct = 0; ct < 4; ++ct) {
          const int ncol = wx * 64 + ct * 16 + l15;        // C/D: col=lane&15
          const int n = tj + ncol;
          const float sim = acc[rt][ct][r] * 5.0f;         // /TEMPERATURE
          const float e = __expf(sim);
          if (offdiag || mrow != ncol) se += e;            // diag excluded
          if (offdiag) colp[ct] += e;
          if (MD[mrow * 128 + ncol]) {                     // sparse positives
            atomicAdd(&possum[m], sim);
            atomicAdd(&cntw[m], 1.0f);
          }
          if (offdiag && MM[ncol * 128 + mrow]) {          // mirror (n, m)
            atomicAdd(&possum[n], sim);
            atomicAdd(&cntw[n], 1.0f);
          }
        }
#pragma unroll
        for (int off = 1; off < 16; off <<= 1) se += __shfl_xor(se, off, 64);
        if (l15 == 0) redrow[mrow][wx] = se;
      }
    }
    if (offdiag) {
#pragma unroll
      for (int ct = 0; ct < 4; ++ct) {
        float ce = colp[ct];
        ce += __shfl_xor(ce, 16, 64);
        ce += __shfl_xor(ce, 32, 64);
        if (qd == 0) redcol[wx * 64 + ct * 16 + l15][wy] = ce;
      }
    }
    __syncthreads();
    if (t < 128) {
      atomicAdd(&rowexp[ti + t], redrow[t][0] + redrow[t][1]);
      if (offdiag) atomicAdd(&rowexp[tj + t], redcol[t][0] + redcol[t][1]);
    }
  }
}

__global__ __launch_bounds__(1024) void finalize(const float* __restrict__ rowexp,
                                                 const float* __restrict__ possum,
                                                 const float* __restrict__ cnt,
                                                 const float* __restrict__ qpart,
                                                 const float* __restrict__ dtot,
                                                 float* __restrict__ out) {
  const int t = threadIdx.x;
  const int wave = t >> 6, lane = t & 63;
  float c = 0.f, q = 0.f;
  for (int m = t; m < 4096; m += 1024) {
    c += logf(rowexp[m]) - possum[m] / fmaxf(cnt[m], 1.0f);
    q += qpart[m];
  }
#pragma unroll
  for (int off = 1; off < 64; off <<= 1) {
    c += __shfl_xor(c, off, 64);
    q += __shfl_xor(q, off, 64);
  }
  __shared__ float sc[16], sq[16];
  if (lane == 0) { sc[wave] = c; sq[wave] = q; }
  __syncthreads();
  if (t == 0) {
    float C = 0.f, Q = 0.f;
    for (int i = 0; i < 16; ++i) { C += sc[i]; Q += sq[i]; }
    // D entries are 128x the true diff -> /(4096^2 * 128^2) on the squared sum
    out[0] = C * (1.0f / 4096.0f) + 0.5f * (dtot[0] * 3.6379788e-12f) +
             0.01f * (Q * (1.0f / 524288.0f));
  }
}

extern "C" void kernel_launch(void* const* d_in, const int* in_sizes, int n_in,
                              void* d_out, int out_size, void* d_ws, size_t ws_size,
                              hipStream_t stream) {
  const float* logits = (const float*)d_in[0];
  const float* hash = (const float*)d_in[1];
  const float* teacher = (const float*)d_in[2];
  const void* mask = d_in[3];
  float* out = (float*)d_out;

  char* ws = (char*)d_ws;
  float* rowexp = (float*)(ws + 0);
  float* possum = (float*)(ws + 16384);
  float* cntw = (float*)(ws + 32768);
  float* qpart = (float*)(ws + 49152);
  float* dtot = (float*)(ws + 65536);
  unsigned short* P = (unsigned short*)(ws + 98304);          // 4096x128 bf16 = 1 MB
  unsigned char* Q = (unsigned char*)(ws + 98304 + 1048576);  // 4096x896 fp8 = 3.5 MB

  prep<<<1024, 256, 0, stream>>>(logits, hash, teacher, P, Q, qpart, rowexp,
                                 possum, cntw, dtot);
  mega<<<1056, 256, 0, stream>>>(P, Q, mask, rowexp, possum, cntw, dtot);
  finalize<<<1, 1024, 0, stream>>>(rowexp, possum, cntw, qpart, dtot, out);
}